// Round 1
// baseline (1997.360 us; speedup 1.0000x reference)
//
#include <hip/hip_runtime.h>
#include <math.h>

#define TT 512
#define BB 32
#define SS 64
#define AA 8
#define DD 32
#define EPSF 1e-6f

__device__ __forceinline__ float wave_sum(float v){
  #pragma unroll
  for (int m = 1; m < 64; m <<= 1) v += __shfl_xor(v, m, 64);
  return v;
}
__device__ __forceinline__ float wave_max(float v){
  #pragma unroll
  for (int m = 1; m < 64; m <<= 1) v = fmaxf(v, __shfl_xor(v, m, 64));
  return v;
}

// --- kernel 0: invvar = exp(-logv) [S*D] and per-state const cs[s] = sum_d logv + D*log(2pi)
__global__ void prep_kernel(const float* __restrict__ logv,
                            float* __restrict__ iv, float* __restrict__ cs){
  int gid = blockIdx.x * blockDim.x + threadIdx.x;
  if (gid < SS * DD) iv[gid] = __expf(-logv[gid]);
  if (gid < SS){
    float s = 0.f;
    #pragma unroll
    for (int d = 0; d < DD; ++d) s += logv[gid * DD + d];
    cs[gid] = s + (float)DD * 1.8378770664093453f;  // D*log(2*pi)
  }
}

// --- kernel 1: logp_x[t,b,s] = -0.5*(sum_d diff^2*iv + cs[s])
__global__ __launch_bounds__(256) void logpx_kernel(
    const float* __restrict__ x, const float* __restrict__ mu,
    const float* __restrict__ iv, const float* __restrict__ cs,
    float* __restrict__ logp_x){
  const int lane = threadIdx.x & 63;
  const int w = threadIdx.x >> 6;
  const int row = blockIdx.x * 4 + w;          // row in [0, T*B)
  const float* __restrict__ xp  = x  + row * DD;   // uniform per wave -> scalar loads
  const float* __restrict__ mup = mu + lane * DD;
  const float* __restrict__ ivp = iv + lane * DD;
  float acc = 0.f;
  #pragma unroll
  for (int d = 0; d < DD; ++d){
    float diff = xp[d] - mup[d];
    acc = fmaf(diff * diff, ivp[d], acc);
  }
  logp_x[row * SS + lane] = -0.5f * (acc + cs[lane]);
}

// --- kernel 2: fused forward+backward chains. blocks [0,B): fwd; [B,2B): bwd.
// 256 threads = 4 waves; wave w owns transition-matrix rows i = 16w+r, lane = column j.
// w_act slice held in registers (128 VGPR/thread) -- 1 block/CU so 512 VGPR budget.
__global__ __launch_bounds__(256, 1) void scan_kernel(
    const float* __restrict__ a, const float* __restrict__ mask,
    const float* __restrict__ init_logits,
    const float* __restrict__ w_base, const float* __restrict__ w_act,
    const float* __restrict__ logp_x,
    float* __restrict__ alpha, float* __restrict__ log_beta){
  const int lane = threadIdx.x & 63;
  const int w = threadIdx.x >> 6;
  const bool is_fwd = (blockIdx.x < BB);
  const int b = is_fwd ? blockIdx.x : (blockIdx.x - BB);

  // preload weight tile: rows i = 16w+r, column = lane
  float wb[16], wa[8][16];
  #pragma unroll
  for (int r = 0; r < 16; ++r){
    const int i = w * 16 + r;
    wb[r] = w_base[i * SS + lane];
    #pragma unroll
    for (int k = 0; k < 8; ++k) wa[k][r] = w_act[(k * SS + i) * SS + lane];
  }

  __shared__ float lds_part[2][4][SS];  // fwd: per-wave column-sum partials (double buffered)
  __shared__ float lds_new[2][SS];      // bwd: new logb gather (double buffered)

  if (is_fwd){
    // alpha0 = softmax(logp_x[0] + init_logits)   (log_softmax shift drops out)
    float v0 = logp_x[b * SS + lane] + init_logits[lane];
    float mx0 = wave_max(v0);
    float e0 = __expf(v0 - mx0);
    float sm0 = wave_sum(e0);
    float areg = e0 * __builtin_amdgcn_rcpf(sm0);   // lane j holds alpha_j
    if (w == 0) alpha[b * SS + lane] = areg;

    for (int t = 1; t < TT; ++t){
      const float* __restrict__ ap = a + ((t - 1) * BB + b) * AA;  // uniform -> s_load
      float aa[8];
      #pragma unroll
      for (int k = 0; k < 8; ++k) aa[k] = ap[k];
      float lx = logp_x[(t * BB + b) * SS + lane];

      float colsum = 0.f;
      #pragma unroll
      for (int r = 0; r < 16; ++r){
        float u = wb[r];
        #pragma unroll
        for (int k = 0; k < 8; ++k) u = fmaf(aa[k], wa[k][r], u);
        float e1 = __expf(u);              // |u| < ~2: no max-shift needed
        float rs = wave_sum(e1);           // row softmax denominator
        float ai = __shfl(areg, w * 16 + r, 64);
        colsum = fmaf(e1, ai * __builtin_amdgcn_rcpf(rs), colsum);  // s_j += p_ij * alpha_i
      }
      const int p = t & 1;
      lds_part[p][w][lane] = colsum;
      __syncthreads();
      float s = lds_part[p][0][lane] + lds_part[p][1][lane]
              + lds_part[p][2][lane] + lds_part[p][3][lane];
      // alpha_new = softmax(lx + log(s+EPS))  ==  normalize( exp(lx-mx)*(s+EPS) )
      float mx = wave_max(lx);
      float e2 = __expf(lx - mx) * (s + EPSF);
      float sm = wave_sum(e2);
      areg = e2 * __builtin_amdgcn_rcpf(sm);
      if (w == 0) alpha[(t * BB + b) * SS + lane] = areg;
    }
  } else {
    // backward: store logb in SHIFTED form (q_z softmax is shift-invariant per (t,b) row),
    // keeping magnitudes small so f32 rounding doesn't accumulate.
    float breg = 0.f;                      // lane j holds logb_j (relative)
    if (w == 0) log_beta[((TT - 1) * BB + b) * SS + lane] = 0.f;

    for (int t = TT - 2; t >= 0; --t){
      const float* __restrict__ ap = a + (t * BB + b) * AA;
      float aa[8];
      #pragma unroll
      for (int k = 0; k < 8; ++k) aa[k] = ap[k];
      float lx = logp_x[((t + 1) * BB + b) * SS + lane];
      float mval = mask[(t + 1) * BB + b];

      float z = lx + breg;
      float M = wave_max(z);
      float wj = __expf(z - M);            // weights, <= 1
      float W = wave_sum(wj);

      float hold = 0.f;
      #pragma unroll
      for (int r = 0; r < 16; ++r){
        float u = wb[r];
        #pragma unroll
        for (int k = 0; k < 8; ++k) u = fmaf(aa[k], wa[k][r], u);
        float e1 = __expf(u);
        float s1 = e1;                     // rowsum
        float s2 = e1 * wj;                // sum_j e_ij * w_j
        #pragma unroll
        for (int m = 1; m < 64; m <<= 1){
          s1 += __shfl_xor(s1, m, 64);
          s2 += __shfl_xor(s2, m, 64);
        }
        // LSE_j(lx + log(p+EPS) + logb) - M - c  =  log( s2/s1 + EPS*W )
        float v = __logf(fmaf(EPSF, W, s2 * __builtin_amdgcn_rcpf(s1)));
        v = (mval == 1.0f) ? v : 0.0f;
        if (lane == r) hold = v;           // lane r stows row (16w+r)'s value
      }
      const int p = t & 1;
      if (lane < 16) lds_new[p][w * 16 + lane] = hold;
      __syncthreads();
      breg = lds_new[p][lane];
      if (w == 0) log_beta[(t * BB + b) * SS + lane] = breg;
    }
  }
}

// --- kernel 3: q_z = softmax(log(alpha+EPS) + log_beta) over states
__global__ __launch_bounds__(256) void qz_kernel(
    const float* __restrict__ alpha, const float* __restrict__ log_beta,
    float* __restrict__ out){
  const int lane = threadIdx.x & 63;
  const int w = threadIdx.x >> 6;
  const int row = blockIdx.x * 4 + w;
  float v = __logf(alpha[row * SS + lane] + EPSF) + log_beta[row * SS + lane];
  float mx = wave_max(v);
  float e = __expf(v - mx);
  float sm = wave_sum(e);
  out[row * SS + lane] = e * __builtin_amdgcn_rcpf(sm);
}

extern "C" void kernel_launch(void* const* d_in, const int* in_sizes, int n_in,
                              void* d_out, int out_size, void* d_ws, size_t ws_size,
                              hipStream_t stream){
  const float* x      = (const float*)d_in[0];
  const float* a      = (const float*)d_in[1];
  const float* mask   = (const float*)d_in[2];
  const float* mu     = (const float*)d_in[3];
  const float* logv   = (const float*)d_in[4];
  const float* il     = (const float*)d_in[5];
  const float* w_base = (const float*)d_in[6];
  const float* w_act  = (const float*)d_in[7];
  float* out = (float*)d_out;

  float* ws = (float*)d_ws;
  float* iv       = ws;                       // 2048
  float* cs       = ws + 2048;                // 64 (padded to 4096)
  float* logp_x   = ws + 4096;                // T*B*S = 1048576
  float* alpha    = logp_x + TT * BB * SS;    // 1048576
  float* log_beta = alpha  + TT * BB * SS;    // 1048576

  prep_kernel<<<8, 256, 0, stream>>>(logv, iv, cs);
  logpx_kernel<<<TT * BB / 4, 256, 0, stream>>>(x, mu, iv, cs, logp_x);
  scan_kernel<<<2 * BB, 256, 0, stream>>>(a, mask, il, w_base, w_act,
                                          logp_x, alpha, log_beta);
  qz_kernel<<<TT * BB / 4, 256, 0, stream>>>(alpha, log_beta, out);
}

// Round 2
// 1996.693 us; speedup vs baseline: 1.0003x; 1.0003x over previous
//
#include <hip/hip_runtime.h>
#include <math.h>

#define TT 512
#define BB 32
#define SS 64
#define AA 8
#define DD 32
#define EPSF 1e-6f
#define SEPS (64.0f * 1e-6f)   // reference sums EPS over the 64 i-terms

__device__ __forceinline__ float wave_sum(float v){
  #pragma unroll
  for (int m = 1; m < 64; m <<= 1) v += __shfl_xor(v, m, 64);
  return v;
}
__device__ __forceinline__ float wave_max(float v){
  #pragma unroll
  for (int m = 1; m < 64; m <<= 1) v = fmaxf(v, __shfl_xor(v, m, 64));
  return v;
}
__device__ __forceinline__ float readlane_f(float v, int l){
  return __int_as_float(__builtin_amdgcn_readlane(__float_as_int(v), l));
}
// raw barrier: does NOT drain vmcnt, so global prefetch loads stay in flight.
#define BARRIER() asm volatile("s_waitcnt lgkmcnt(0)\n\ts_barrier" ::: "memory")

// --- kernel 0: invvar = exp(-logv), cs[s] = sum_d logv + D*log(2pi)
__global__ void prep_kernel(const float* __restrict__ logv,
                            float* __restrict__ iv, float* __restrict__ cs){
  int gid = blockIdx.x * blockDim.x + threadIdx.x;
  if (gid < SS * DD) iv[gid] = __expf(-logv[gid]);
  if (gid < SS){
    float s = 0.f;
    #pragma unroll
    for (int d = 0; d < DD; ++d) s += logv[gid * DD + d];
    cs[gid] = s + (float)DD * 1.8378770664093453f;
  }
}

// --- kernel 1: lx[t,b,s] and elx = exp(lx - rowmax)
__global__ __launch_bounds__(256) void logpx_kernel(
    const float* __restrict__ x, const float* __restrict__ mu,
    const float* __restrict__ iv, const float* __restrict__ cs,
    float* __restrict__ lx_out, float* __restrict__ elx_out){
  const int lane = threadIdx.x & 63;
  const int w = threadIdx.x >> 6;
  const int row = blockIdx.x * 4 + w;
  const float* __restrict__ xp  = x  + row * DD;
  const float* __restrict__ mup = mu + lane * DD;
  const float* __restrict__ ivp = iv + lane * DD;
  float acc = 0.f;
  #pragma unroll
  for (int d = 0; d < DD; ++d){
    float diff = xp[d] - mup[d];
    acc = fmaf(diff * diff, ivp[d], acc);
  }
  float lx = -0.5f * (acc + cs[lane]);
  float mx = wave_max(lx);
  lx_out[row * SS + lane]  = lx;
  elx_out[row * SS + lane] = __expf(lx - mx);
}

// --- kernel 2: P[t,b,i,j] = row-softmax of (w_base + a[t,b]·w_act). Fully parallel.
__global__ __launch_bounds__(256, 2) void trans_kernel(
    const float* __restrict__ a, const float* __restrict__ w_base,
    const float* __restrict__ w_act, float* __restrict__ P){
  const int lane = threadIdx.x & 63;
  const int w = threadIdx.x >> 6;
  const int t = blockIdx.x >> 5;          // BB = 32
  const int b = blockIdx.x & 31;
  const float* __restrict__ ap = a + (t * BB + b) * AA;
  float aa[8];
  #pragma unroll
  for (int k = 0; k < 8; ++k) aa[k] = ap[k];
  float* __restrict__ Pout = P + (((size_t)(t * BB + b)) << 12);
  #pragma unroll
  for (int r = 0; r < 16; ++r){
    const int i = w * 16 + r;
    float u = w_base[i * SS + lane];
    #pragma unroll
    for (int k = 0; k < 8; ++k) u = fmaf(aa[k], w_act[(k * SS + i) * SS + lane], u);
    float e = __expf(u);                  // |u| small: no max-shift needed
    float rs = wave_sum(e);
    Pout[i * SS + lane] = e * __builtin_amdgcn_rcpf(rs);
  }
}

// --- kernel 3: fused scans. blocks [0,B): fwd; [B,2B): bwd.
// Per step: 16 prefetched global loads of P rows + readlane/FMA matvec.
__global__ __launch_bounds__(256, 2) void scan_kernel(
    const float* __restrict__ lx, const float* __restrict__ elx,
    const float* __restrict__ mask, const float* __restrict__ init_logits,
    const float* __restrict__ P,
    float* __restrict__ alpha, float* __restrict__ log_beta){
  const int lane = threadIdx.x & 63;
  const int w = threadIdx.x >> 6;
  const int wb16 = __builtin_amdgcn_readfirstlane(w * 16);  // SGPR for readlane idx

  __shared__ float fpart[2][4][SS];   // fwd partial combine (parity buffered)
  __shared__ float st[SS * 65];       // bwd staged trans (padded rows)
  __shared__ float bpart[4][SS];      // bwd partial combine

  if (blockIdx.x < BB){
    // ---------------- FORWARD ----------------
    const int b = blockIdx.x;
    // u = unnormalized alpha, c = 1/sum(u) (wave-uniform, folded in late)
    float z0 = lx[b * SS + lane] + init_logits[lane];
    float mx0 = wave_max(z0);
    float u = __expf(z0 - mx0);
    float c = __builtin_amdgcn_rcpf(wave_sum(u));
    if (w == 0) alpha[b * SS + lane] = u * c;

    float pc[16], pn[16];
    {
      const float* __restrict__ Pp = P + (((size_t)b) << 12) + wb16 * SS + lane;
      #pragma unroll
      for (int r = 0; r < 16; ++r) pc[r] = Pp[r * SS];
    }
    float ec = elx[(1 * BB + b) * SS + lane];
    float en;

    auto step = [&](int t, float (&pcu)[16], float (&pnx)[16], float& ecur, float& enxt){
      // prefetch trans index t (used at step t+1), clamped
      const int tp = (t <= TT - 2) ? t : (TT - 2);
      const float* __restrict__ Pp = P + (((size_t)(tp * BB + b)) << 12) + wb16 * SS + lane;
      #pragma unroll
      for (int r = 0; r < 16; ++r) pnx[r] = Pp[r * SS];
      const int te = (t + 1 <= TT - 1) ? (t + 1) : (TT - 1);
      enxt = elx[(te * BB + b) * SS + lane];
      // matvec partial: s_j += u_i * p_ij  (i in this wave's 16 rows)
      float a0 = 0.f, a1 = 0.f, a2 = 0.f, a3 = 0.f;
      #pragma unroll
      for (int r = 0; r < 16; r += 4){
        a0 = fmaf(readlane_f(u, wb16 + r),     pcu[r],     a0);
        a1 = fmaf(readlane_f(u, wb16 + r + 1), pcu[r + 1], a1);
        a2 = fmaf(readlane_f(u, wb16 + r + 2), pcu[r + 2], a2);
        a3 = fmaf(readlane_f(u, wb16 + r + 3), pcu[r + 3], a3);
      }
      const int par = t & 1;
      fpart[par][w][lane] = (a0 + a1) + (a2 + a3);
      BARRIER();
      float comb = (fpart[par][0][lane] + fpart[par][1][lane])
                 + (fpart[par][2][lane] + fpart[par][3][lane]);
      // alpha' ∝ elx * (c*comb + 64*EPS)
      float u2 = ecur * fmaf(c, comb, SEPS);
      float c2 = __builtin_amdgcn_rcpf(wave_sum(u2));
      if (w == 0) alpha[(t * BB + b) * SS + lane] = u2 * c2;
      u = u2; c = c2;
    };

    for (int t = 1; t < TT; t += 2){
      step(t, pc, pn, ec, en);
      if (t + 1 < TT) step(t + 1, pn, pc, en, ec);
    }
  } else {
    // ---------------- BACKWARD ----------------
    const int b = blockIdx.x - BB;
    float breg = 0.f;                    // relative log-beta (shift-covariant)
    if (w == 0) log_beta[((TT - 1) * BB + b) * SS + lane] = 0.f;

    float pc[16], pn[16];
    {
      const float* __restrict__ Pp = P + (((size_t)((TT - 2) * BB + b)) << 12) + wb16 * SS + lane;
      #pragma unroll
      for (int r = 0; r < 16; ++r) pc[r] = Pp[r * SS];
    }
    float lxc = lx[((TT - 1) * BB + b) * SS + lane];
    float lxn;
    float mc = mask[(TT - 1) * BB + b];
    float mn;

    auto step = [&](int t, float (&pcu)[16], float (&pnx)[16],
                    float& lxcur, float& lxnxt, float& mcur, float& mnxt){
      // stage this step's trans rows into LDS (latency overlaps w computation)
      #pragma unroll
      for (int r = 0; r < 16; ++r) st[(wb16 + r) * 65 + lane] = pcu[r];
      float z = lxcur + breg;
      float M = wave_max(z);
      float wgt = __expf(z - M);
      float W = wave_sum(wgt);
      // prefetch trans index t-1, lx[t], mask[t] (clamped)
      const int tp = (t >= 1) ? (t - 1) : 0;
      const float* __restrict__ Pp = P + (((size_t)(tp * BB + b)) << 12) + wb16 * SS + lane;
      #pragma unroll
      for (int r = 0; r < 16; ++r) pnx[r] = Pp[r * SS];
      const int te = (t >= 1) ? t : 0;
      lxnxt = lx[(te * BB + b) * SS + lane];
      mnxt = mask[te * BB + b];
      BARRIER();                         // B1: stage visible
      // dot_i = sum_j p_ij * w_j  (this wave's 16-j chunk, lane = i)
      float a0 = 0.f, a1 = 0.f, a2 = 0.f, a3 = 0.f;
      #pragma unroll
      for (int jj = 0; jj < 16; jj += 4){
        a0 = fmaf(readlane_f(wgt, wb16 + jj),     st[lane * 65 + wb16 + jj],     a0);
        a1 = fmaf(readlane_f(wgt, wb16 + jj + 1), st[lane * 65 + wb16 + jj + 1], a1);
        a2 = fmaf(readlane_f(wgt, wb16 + jj + 2), st[lane * 65 + wb16 + jj + 2], a2);
        a3 = fmaf(readlane_f(wgt, wb16 + jj + 3), st[lane * 65 + wb16 + jj + 3], a3);
      }
      bpart[w][lane] = (a0 + a1) + (a2 + a3);
      BARRIER();                         // B2: partials visible
      float dot = (bpart[0][lane] + bpart[1][lane]) + (bpart[2][lane] + bpart[3][lane]);
      float v = __logf(fmaf(EPSF, W, dot));   // log(dot + EPS*sum(w))
      breg = (mcur == 1.0f) ? v : 0.0f;
      if (w == 0) log_beta[(t * BB + b) * SS + lane] = breg;
    };

    for (int t = TT - 2; t >= 0; t -= 2){
      step(t, pc, pn, lxc, lxn, mc, mn);
      if (t - 1 >= 0) step(t - 1, pn, pc, lxn, lxc, mn, mc);
    }
  }
}

// --- fallback scan (previous passing version) if workspace too small for P
__global__ __launch_bounds__(256, 1) void scan_fallback(
    const float* __restrict__ a, const float* __restrict__ mask,
    const float* __restrict__ init_logits,
    const float* __restrict__ w_base, const float* __restrict__ w_act,
    const float* __restrict__ logp_x,
    float* __restrict__ alpha, float* __restrict__ log_beta){
  const int lane = threadIdx.x & 63;
  const int w = threadIdx.x >> 6;
  const bool is_fwd = (blockIdx.x < BB);
  const int b = is_fwd ? blockIdx.x : (blockIdx.x - BB);
  float wb[16], wa[8][16];
  #pragma unroll
  for (int r = 0; r < 16; ++r){
    const int i = w * 16 + r;
    wb[r] = w_base[i * SS + lane];
    #pragma unroll
    for (int k = 0; k < 8; ++k) wa[k][r] = w_act[(k * SS + i) * SS + lane];
  }
  __shared__ float lds_part[2][4][SS];
  __shared__ float lds_new[2][SS];
  if (is_fwd){
    float v0 = logp_x[b * SS + lane] + init_logits[lane];
    float mx0 = wave_max(v0);
    float e0 = __expf(v0 - mx0);
    float sm0 = wave_sum(e0);
    float areg = e0 * __builtin_amdgcn_rcpf(sm0);
    if (w == 0) alpha[b * SS + lane] = areg;
    for (int t = 1; t < TT; ++t){
      const float* __restrict__ ap = a + ((t - 1) * BB + b) * AA;
      float aa[8];
      #pragma unroll
      for (int k = 0; k < 8; ++k) aa[k] = ap[k];
      float lxv = logp_x[(t * BB + b) * SS + lane];
      float colsum = 0.f;
      #pragma unroll
      for (int r = 0; r < 16; ++r){
        float u = wb[r];
        #pragma unroll
        for (int k = 0; k < 8; ++k) u = fmaf(aa[k], wa[k][r], u);
        float e1 = __expf(u);
        float rs = wave_sum(e1);
        float ai = __shfl(areg, w * 16 + r, 64);
        colsum = fmaf(e1, ai * __builtin_amdgcn_rcpf(rs), colsum);
      }
      const int p = t & 1;
      lds_part[p][w][lane] = colsum;
      __syncthreads();
      float s = lds_part[p][0][lane] + lds_part[p][1][lane]
              + lds_part[p][2][lane] + lds_part[p][3][lane];
      float mx = wave_max(lxv);
      float e2 = __expf(lxv - mx) * (s + EPSF);
      float sm = wave_sum(e2);
      areg = e2 * __builtin_amdgcn_rcpf(sm);
      if (w == 0) alpha[(t * BB + b) * SS + lane] = areg;
    }
  } else {
    float breg = 0.f;
    if (w == 0) log_beta[((TT - 1) * BB + b) * SS + lane] = 0.f;
    for (int t = TT - 2; t >= 0; --t){
      const float* __restrict__ ap = a + (t * BB + b) * AA;
      float aa[8];
      #pragma unroll
      for (int k = 0; k < 8; ++k) aa[k] = ap[k];
      float lxv = logp_x[((t + 1) * BB + b) * SS + lane];
      float mval = mask[(t + 1) * BB + b];
      float z = lxv + breg;
      float M = wave_max(z);
      float wj = __expf(z - M);
      float W = wave_sum(wj);
      float hold = 0.f;
      #pragma unroll
      for (int r = 0; r < 16; ++r){
        float u = wb[r];
        #pragma unroll
        for (int k = 0; k < 8; ++k) u = fmaf(aa[k], wa[k][r], u);
        float e1 = __expf(u);
        float s1 = e1;
        float s2 = e1 * wj;
        #pragma unroll
        for (int m = 1; m < 64; m <<= 1){
          s1 += __shfl_xor(s1, m, 64);
          s2 += __shfl_xor(s2, m, 64);
        }
        float v = __logf(fmaf(EPSF, W, s2 * __builtin_amdgcn_rcpf(s1)));
        v = (mval == 1.0f) ? v : 0.0f;
        if (lane == r) hold = v;
      }
      const int p = t & 1;
      if (lane < 16) lds_new[p][w * 16 + lane] = hold;
      __syncthreads();
      breg = lds_new[p][lane];
      if (w == 0) log_beta[(t * BB + b) * SS + lane] = breg;
    }
  }
}

// --- kernel 4: q_z = softmax(log(alpha+EPS) + log_beta)
__global__ __launch_bounds__(256) void qz_kernel(
    const float* __restrict__ alpha, const float* __restrict__ log_beta,
    float* __restrict__ out){
  const int lane = threadIdx.x & 63;
  const int w = threadIdx.x >> 6;
  const int row = blockIdx.x * 4 + w;
  float v = __logf(alpha[row * SS + lane] + EPSF) + log_beta[row * SS + lane];
  float mx = wave_max(v);
  float e = __expf(v - mx);
  float sm = wave_sum(e);
  out[row * SS + lane] = e * __builtin_amdgcn_rcpf(sm);
}

extern "C" void kernel_launch(void* const* d_in, const int* in_sizes, int n_in,
                              void* d_out, int out_size, void* d_ws, size_t ws_size,
                              hipStream_t stream){
  const float* x      = (const float*)d_in[0];
  const float* a      = (const float*)d_in[1];
  const float* mask   = (const float*)d_in[2];
  const float* mu     = (const float*)d_in[3];
  const float* logv   = (const float*)d_in[4];
  const float* il     = (const float*)d_in[5];
  const float* w_base = (const float*)d_in[6];
  const float* w_act  = (const float*)d_in[7];
  float* out = (float*)d_out;

  float* ws = (float*)d_ws;
  const size_t TBS = (size_t)TT * BB * SS;
  float* iv       = ws;                   // 2048 (+ cs, padded to 4096)
  float* cs       = ws + 2048;
  float* lx       = ws + 4096;
  float* elx      = lx + TBS;
  float* alpha    = elx + TBS;
  float* log_beta = alpha + TBS;
  float* P        = log_beta + TBS;       // 511*32*4096 floats = 268 MB
  const size_t P_floats = (size_t)(TT - 1) * BB * SS * SS;
  const size_t need_bytes = (4096 + 4 * TBS + P_floats) * sizeof(float);

  prep_kernel<<<8, 256, 0, stream>>>(logv, iv, cs);
  logpx_kernel<<<TT * BB / 4, 256, 0, stream>>>(x, mu, iv, cs, lx, elx);
  if (ws_size >= need_bytes){
    trans_kernel<<<(TT - 1) * BB, 256, 0, stream>>>(a, w_base, w_act, P);
    scan_kernel<<<2 * BB, 256, 0, stream>>>(lx, elx, mask, il, P, alpha, log_beta);
  } else {
    scan_fallback<<<2 * BB, 256, 0, stream>>>(a, mask, il, w_base, w_act, lx,
                                              alpha, log_beta);
  }
  qz_kernel<<<TT * BB / 4, 256, 0, stream>>>(alpha, log_beta, out);
}

// Round 3
// 543.089 us; speedup vs baseline: 3.6778x; 3.6765x over previous
//
#include <hip/hip_runtime.h>
#include <math.h>

#define TT 512
#define BB 32
#define SS 64
#define AA 8
#define DD 32
#define EPSF 1e-6f
#define SEPS (64.0f * 1e-6f)   // reference adds EPS under the sum over 64 i-terms
#define TS 68                  // padded tile row stride (floats): 16B-aligned, breaks pow2 banks

__device__ __forceinline__ float wave_sum(float v){
  #pragma unroll
  for (int m = 1; m < 64; m <<= 1) v += __shfl_xor(v, m, 64);
  return v;
}
__device__ __forceinline__ float wave_max(float v){
  #pragma unroll
  for (int m = 1; m < 64; m <<= 1) v = fmaxf(v, __shfl_xor(v, m, 64));
  return v;
}
__device__ __forceinline__ float readlane_f(float v, int l){
  return __int_as_float(__builtin_amdgcn_readlane(__float_as_int(v), l));
}
__device__ __forceinline__ void pin(float& x){ asm volatile("" : "+v"(x)); }
// raw barrier: drains LDS only; global prefetch loads stay in flight (no vmcnt drain)
#define BARRIER() asm volatile("s_waitcnt lgkmcnt(0)\n\ts_barrier" ::: "memory")

// --- kernel 0: invvar = exp(-logv), cs[s] = sum_d logv + D*log(2pi)
__global__ void prep_kernel(const float* __restrict__ logv,
                            float* __restrict__ iv, float* __restrict__ cs){
  int gid = blockIdx.x * blockDim.x + threadIdx.x;
  if (gid < SS * DD) iv[gid] = __expf(-logv[gid]);
  if (gid < SS){
    float s = 0.f;
    #pragma unroll
    for (int d = 0; d < DD; ++d) s += logv[gid * DD + d];
    cs[gid] = s + (float)DD * 1.8378770664093453f;
  }
}

// --- kernel 1: slx[t,b,s] = lx - rowmax(lx)  (shift makes exp() overflow-safe everywhere)
__global__ __launch_bounds__(256) void logpx_kernel(
    const float* __restrict__ x, const float* __restrict__ mu,
    const float* __restrict__ iv, const float* __restrict__ cs,
    float* __restrict__ slx_out){
  const int lane = threadIdx.x & 63;
  const int w = threadIdx.x >> 6;
  const int row = blockIdx.x * 4 + w;
  const float* __restrict__ xp  = x  + row * DD;
  const float* __restrict__ mup = mu + lane * DD;
  const float* __restrict__ ivp = iv + lane * DD;
  float acc = 0.f;
  #pragma unroll
  for (int d = 0; d < DD; ++d){
    float diff = xp[d] - mup[d];
    acc = fmaf(diff * diff, ivp[d], acc);
  }
  float lx = -0.5f * (acc + cs[lane]);
  float mx = wave_max(lx);
  slx_out[row * SS + lane] = lx - mx;
}

// --- kernel 2: fused pipelined scans. blocks [0,B): fwd; [B,2B): bwd. 768 thr = 12 waves.
// waves 0-3: consumers (the serial chain). waves 4-11: producers (trans tile for step s+1).
__global__ __launch_bounds__(768) void scan_kernel(
    const float* __restrict__ slx, const float* __restrict__ mask,
    const float* __restrict__ il, const float* __restrict__ a,
    const float* __restrict__ w_base, const float* __restrict__ w_act,
    float* __restrict__ alpha, float* __restrict__ log_beta){
  const int lane = threadIdx.x & 63;
  const int w    = threadIdx.x >> 6;
  const bool is_fwd = (blockIdx.x < BB);
  const int b = is_fwd ? blockIdx.x : (blockIdx.x - BB);

  // fwd tile stored TRANSPOSED [j][i]; bwd tile [i][j] -- each block has one direction.
  __shared__ __align__(16) float tile[2][SS * TS];
  __shared__ float rsp[2][8][SS];     // row-sum partials (8 producer waves)
  __shared__ float fpart[2][4][SS];   // consumer matvec partials

  if (w >= 4){
    // ======================= PRODUCERS =======================
    const int pw = __builtin_amdgcn_readfirstlane(w - 4);
    const int jbase = pw * 8;        // this wave's 8-column chunk; lane = row i
    float wbv[8], wav[8][8];
    #pragma unroll
    for (int jj = 0; jj < 8; ++jj){
      wbv[jj] = w_base[lane * SS + jbase + jj]; pin(wbv[jj]);
      #pragma unroll
      for (int k = 0; k < 8; ++k){
        wav[k][jj] = w_act[(k * SS + lane) * SS + jbase + jj]; pin(wav[k][jj]);
      }
    }
    float aa[8], aan[8];
    {
      const int tp = is_fwd ? 0 : (TT - 2);
      const float* __restrict__ ap = a + (tp * BB + b) * AA;
      #pragma unroll
      for (int k = 0; k < 8; ++k) aa[k] = ap[k];
    }
    {
      const int tn0 = is_fwd ? 1 : (TT - 3);
      const float* __restrict__ ap = a + (tn0 * BB + b) * AA;
      #pragma unroll
      for (int k = 0; k < 8; ++k) aan[k] = ap[k];
    }
    // prologue: tile for first consumer step -> buf 0
    {
      float racc = 0.f, ev[8];
      #pragma unroll
      for (int jj = 0; jj < 8; ++jj){
        float u = wbv[jj];
        #pragma unroll
        for (int k = 0; k < 8; ++k) u = fmaf(aa[k], wav[k][jj], u);
        float e = __expf(u);
        racc += e; ev[jj] = e;
        if (is_fwd) tile[0][(jbase + jj) * TS + lane] = e;
      }
      if (!is_fwd){
        *(float4*)&tile[0][lane * TS + jbase]     = make_float4(ev[0], ev[1], ev[2], ev[3]);
        *(float4*)&tile[0][lane * TS + jbase + 4] = make_float4(ev[4], ev[5], ev[6], ev[7]);
      }
      rsp[0][pw][lane] = racc;
    }
    BARRIER();  // prologue
    for (int s = 0; s < TT - 1; ++s){
      if (s + 1 <= TT - 2){
        const int buf = (s + 1) & 1;
        #pragma unroll
        for (int k = 0; k < 8; ++k) aa[k] = aan[k];
        if (s + 2 <= TT - 2){
          const int tn = is_fwd ? (s + 2) : (TT - 4 - s);
          const float* __restrict__ ap = a + (tn * BB + b) * AA;
          #pragma unroll
          for (int k = 0; k < 8; ++k) aan[k] = ap[k];
        }
        float racc = 0.f, ev[8];
        #pragma unroll
        for (int jj = 0; jj < 8; ++jj){
          float u = wbv[jj];
          #pragma unroll
          for (int k = 0; k < 8; ++k) u = fmaf(aa[k], wav[k][jj], u);
          float e = __expf(u);
          racc += e; ev[jj] = e;
          if (is_fwd) tile[buf][(jbase + jj) * TS + lane] = e;
        }
        if (!is_fwd){
          *(float4*)&tile[buf][lane * TS + jbase]     = make_float4(ev[0], ev[1], ev[2], ev[3]);
          *(float4*)&tile[buf][lane * TS + jbase + 4] = make_float4(ev[4], ev[5], ev[6], ev[7]);
        }
        rsp[buf][pw][lane] = racc;
      }
      BARRIER();  // B1
      BARRIER();  // B2
    }
  } else {
    // ======================= CONSUMERS =======================
    const int wb16 = __builtin_amdgcn_readfirstlane(w * 16);
    if (is_fwd){
      float z0 = slx[b * SS + lane] + il[lane];
      float u = __expf(z0 - wave_max(z0));   // unnormalized alpha_0
      float slxn = slx[(1 * BB + b) * SS + lane];
      BARRIER();  // prologue
      for (int s = 0; s < TT - 1; ++s){
        const int t = s + 1;
        const int par = s & 1;
        float slxc = slxn;
        if (t + 1 <= TT - 1) slxn = slx[((t + 1) * BB + b) * SS + lane];
        // deferred normalizer: butterfly overlaps the matvec below
        float cprev = __builtin_amdgcn_rcpf(wave_sum(u));
        if (w == 0) alpha[((t - 1) * BB + b) * SS + lane] = u * cprev;
        float rs = ((rsp[par][0][lane] + rsp[par][1][lane]) + (rsp[par][2][lane] + rsp[par][3][lane]))
                 + ((rsp[par][4][lane] + rsp[par][5][lane]) + (rsp[par][6][lane] + rsp[par][7][lane]));
        float va = u * __builtin_amdgcn_rcpf(rs);   // u_i / rs_i (lane = i)
        const float4 p0 = *(const float4*)&tile[par][lane * TS + wb16];
        const float4 p1 = *(const float4*)&tile[par][lane * TS + wb16 + 4];
        const float4 p2 = *(const float4*)&tile[par][lane * TS + wb16 + 8];
        const float4 p3 = *(const float4*)&tile[par][lane * TS + wb16 + 12];
        float a0 = 0.f, a1 = 0.f, a2 = 0.f, a3 = 0.f;
        a0 = fmaf(readlane_f(va, wb16 + 0),  p0.x, a0);
        a1 = fmaf(readlane_f(va, wb16 + 1),  p0.y, a1);
        a2 = fmaf(readlane_f(va, wb16 + 2),  p0.z, a2);
        a3 = fmaf(readlane_f(va, wb16 + 3),  p0.w, a3);
        a0 = fmaf(readlane_f(va, wb16 + 4),  p1.x, a0);
        a1 = fmaf(readlane_f(va, wb16 + 5),  p1.y, a1);
        a2 = fmaf(readlane_f(va, wb16 + 6),  p1.z, a2);
        a3 = fmaf(readlane_f(va, wb16 + 7),  p1.w, a3);
        a0 = fmaf(readlane_f(va, wb16 + 8),  p2.x, a0);
        a1 = fmaf(readlane_f(va, wb16 + 9),  p2.y, a1);
        a2 = fmaf(readlane_f(va, wb16 + 10), p2.z, a2);
        a3 = fmaf(readlane_f(va, wb16 + 11), p2.w, a3);
        a0 = fmaf(readlane_f(va, wb16 + 12), p3.x, a0);
        a1 = fmaf(readlane_f(va, wb16 + 13), p3.y, a1);
        a2 = fmaf(readlane_f(va, wb16 + 14), p3.z, a2);
        a3 = fmaf(readlane_f(va, wb16 + 15), p3.w, a3);
        fpart[par][w][lane] = (a0 + a1) + (a2 + a3);
        BARRIER();  // B1
        float S = (fpart[par][0][lane] + fpart[par][1][lane])
                + (fpart[par][2][lane] + fpart[par][3][lane]);
        float elx = __expf(slxc);
        u = elx * fmaf(cprev, S, SEPS);   // alpha' (unnormalized)
        BARRIER();  // B2
      }
      float cl = __builtin_amdgcn_rcpf(wave_sum(u));
      if (w == 0) alpha[((TT - 1) * BB + b) * SS + lane] = u * cl;
    } else {
      // bwd: breg stored relative, renormalized by log(W) each step -> breg in [ln EPS, ~0],
      // so exp(slx+breg) never overflows and W never flushes to 0. No max-butterfly on path.
      float breg = 0.f;
      if (w == 0) log_beta[((TT - 1) * BB + b) * SS + lane] = 0.f;
      float slxn = slx[((TT - 1) * BB + b) * SS + lane];
      float mn = mask[(TT - 1) * BB + b];
      BARRIER();  // prologue
      for (int s = 0; s < TT - 1; ++s){
        const int t = TT - 2 - s;
        const int par = s & 1;
        float slxc = slxn;
        float mc = mn;
        if (t >= 1){ slxn = slx[(t * BB + b) * SS + lane]; mn = mask[t * BB + b]; }
        float wgt = __expf(slxc + breg);          // lane = j
        float W  = wave_sum(wgt);                 // overlaps matvec
        float rW = __builtin_amdgcn_rcpf(W);
        float rs = ((rsp[par][0][lane] + rsp[par][1][lane]) + (rsp[par][2][lane] + rsp[par][3][lane]))
                 + ((rsp[par][4][lane] + rsp[par][5][lane]) + (rsp[par][6][lane] + rsp[par][7][lane]));
        float rr = __builtin_amdgcn_rcpf(rs);     // 1/rs_i (lane = i)
        const float4 e0 = *(const float4*)&tile[par][lane * TS + wb16];
        const float4 e1 = *(const float4*)&tile[par][lane * TS + wb16 + 4];
        const float4 e2 = *(const float4*)&tile[par][lane * TS + wb16 + 8];
        const float4 e3 = *(const float4*)&tile[par][lane * TS + wb16 + 12];
        float a0 = 0.f, a1 = 0.f, a2 = 0.f, a3 = 0.f;
        a0 = fmaf(readlane_f(wgt, wb16 + 0),  e0.x, a0);
        a1 = fmaf(readlane_f(wgt, wb16 + 1),  e0.y, a1);
        a2 = fmaf(readlane_f(wgt, wb16 + 2),  e0.z, a2);
        a3 = fmaf(readlane_f(wgt, wb16 + 3),  e0.w, a3);
        a0 = fmaf(readlane_f(wgt, wb16 + 4),  e1.x, a0);
        a1 = fmaf(readlane_f(wgt, wb16 + 5),  e1.y, a1);
        a2 = fmaf(readlane_f(wgt, wb16 + 6),  e1.z, a2);
        a3 = fmaf(readlane_f(wgt, wb16 + 7),  e1.w, a3);
        a0 = fmaf(readlane_f(wgt, wb16 + 8),  e2.x, a0);
        a1 = fmaf(readlane_f(wgt, wb16 + 9),  e2.y, a1);
        a2 = fmaf(readlane_f(wgt, wb16 + 10), e2.z, a2);
        a3 = fmaf(readlane_f(wgt, wb16 + 11), e2.w, a3);
        a0 = fmaf(readlane_f(wgt, wb16 + 12), e3.x, a0);
        a1 = fmaf(readlane_f(wgt, wb16 + 13), e3.y, a1);
        a2 = fmaf(readlane_f(wgt, wb16 + 14), e3.z, a2);
        a3 = fmaf(readlane_f(wgt, wb16 + 15), e3.w, a3);
        fpart[par][w][lane] = (a0 + a1) + (a2 + a3);
        BARRIER();  // B1
        float ehat = (fpart[par][0][lane] + fpart[par][1][lane])
                   + (fpart[par][2][lane] + fpart[par][3][lane]);
        // v = log( dot/W + EPS ) = LSE - (shift + log W): uniform shift, bounded output
        float v = __logf(fmaf(ehat * rr, rW, EPSF));
        breg = (mc == 1.0f) ? v : 0.0f;
        if (w == 0) log_beta[(t * BB + b) * SS + lane] = breg;
        BARRIER();  // B2
      }
    }
  }
}

// --- kernel 3: q_z = softmax(log(alpha+EPS) + log_beta) over states
__global__ __launch_bounds__(256) void qz_kernel(
    const float* __restrict__ alpha, const float* __restrict__ log_beta,
    float* __restrict__ out){
  const int lane = threadIdx.x & 63;
  const int w = threadIdx.x >> 6;
  const int row = blockIdx.x * 4 + w;
  float v = __logf(alpha[row * SS + lane] + EPSF) + log_beta[row * SS + lane];
  float mx = wave_max(v);
  float e = __expf(v - mx);
  float sm = wave_sum(e);
  out[row * SS + lane] = e * __builtin_amdgcn_rcpf(sm);
}

extern "C" void kernel_launch(void* const* d_in, const int* in_sizes, int n_in,
                              void* d_out, int out_size, void* d_ws, size_t ws_size,
                              hipStream_t stream){
  const float* x      = (const float*)d_in[0];
  const float* a      = (const float*)d_in[1];
  const float* mask   = (const float*)d_in[2];
  const float* mu     = (const float*)d_in[3];
  const float* logv   = (const float*)d_in[4];
  const float* il     = (const float*)d_in[5];
  const float* w_base = (const float*)d_in[6];
  const float* w_act  = (const float*)d_in[7];
  float* out = (float*)d_out;

  float* ws = (float*)d_ws;
  const size_t TBS = (size_t)TT * BB * SS;
  float* iv       = ws;               // 2048 floats (+ cs, padded to 4096)
  float* cs       = ws + 2048;
  float* slx      = ws + 4096;        // TBS
  float* alpha    = slx + TBS;        // TBS
  float* log_beta = alpha + TBS;      // TBS  -> total 12.6 MB

  prep_kernel<<<8, 256, 0, stream>>>(logv, iv, cs);
  logpx_kernel<<<TT * BB / 4, 256, 0, stream>>>(x, mu, iv, cs, slx);
  scan_kernel<<<2 * BB, 768, 0, stream>>>(slx, mask, il, a, w_base, w_act,
                                          alpha, log_beta);
  qz_kernel<<<TT * BB / 4, 256, 0, stream>>>(alpha, log_beta, out);
}

// Round 5
// 402.461 us; speedup vs baseline: 4.9629x; 1.3494x over previous
//
#include <hip/hip_runtime.h>
#include <math.h>

#define TT 512
#define BB 32
#define SS 64
#define AA 8
#define DD 32
#define EPSF 1e-6f
#define SEPS (64.0f * 1e-6f)   // reference adds EPS under the 64-term i-sum
#define TS 68                  // tile row stride (floats): 16B aligned, breaks pow2

__device__ __forceinline__ int   f2i(float x){ return __float_as_int(x); }
__device__ __forceinline__ float i2f(int x){ return __int_as_float(x); }
__device__ __forceinline__ float readlane_f(float v, int l){
  return i2f(__builtin_amdgcn_readlane(f2i(v), l));
}
// DPP add stage: ctrl/rmask must be compile-time constants -> template params
template<int CTRL, int RMASK>
__device__ __forceinline__ float dpp_add(float x){
  return x + i2f(__builtin_amdgcn_update_dpp(0, f2i(x), CTRL, RMASK, 0xf, true));
}
// full 64-lane sum via DPP (VALU only, no LDS pipe), broadcast via readlane 63
__device__ __forceinline__ float wave_sum_dpp(float x){
  x = dpp_add<0x111, 0xf>(x);  // row_shr:1
  x = dpp_add<0x112, 0xf>(x);  // row_shr:2
  x = dpp_add<0x114, 0xf>(x);  // row_shr:4
  x = dpp_add<0x118, 0xf>(x);  // row_shr:8
  x = dpp_add<0x142, 0xa>(x);  // row_bcast:15 -> rows 1,3
  x = dpp_add<0x143, 0xc>(x);  // row_bcast:31 -> rows 2,3
  return readlane_f(x, 63);
}
// shuffle helpers for the small parallel kernels (latency hidden by occupancy)
__device__ __forceinline__ float wave_sum(float v){
  #pragma unroll
  for (int m = 1; m < 64; m <<= 1) v += __shfl_xor(v, m, 64);
  return v;
}
__device__ __forceinline__ float wave_max(float v){
  #pragma unroll
  for (int m = 1; m < 64; m <<= 1) v = fmaxf(v, __shfl_xor(v, m, 64));
  return v;
}
// raw barrier: drains LDS only; global prefetch loads stay in flight
#define BARRIER() asm volatile("s_waitcnt lgkmcnt(0)\n\ts_barrier" ::: "memory")

// --- kernel 0: invvar = exp(-logv), cs[s] = sum_d logv + D*log(2pi)
__global__ void prep_kernel(const float* __restrict__ logv,
                            float* __restrict__ iv, float* __restrict__ cs){
  int gid = blockIdx.x * blockDim.x + threadIdx.x;
  if (gid < SS * DD) iv[gid] = __expf(-logv[gid]);
  if (gid < SS){
    float s = 0.f;
    #pragma unroll
    for (int d = 0; d < DD; ++d) s += logv[gid * DD + d];
    cs[gid] = s + (float)DD * 1.8378770664093453f;
  }
}

// --- kernel 1: slx[t,b,s] = lx - rowmax(lx)
__global__ __launch_bounds__(256) void logpx_kernel(
    const float* __restrict__ x, const float* __restrict__ mu,
    const float* __restrict__ iv, const float* __restrict__ cs,
    float* __restrict__ slx_out){
  const int lane = threadIdx.x & 63;
  const int w = threadIdx.x >> 6;
  const int row = blockIdx.x * 4 + w;
  const float* __restrict__ xp  = x  + row * DD;
  const float* __restrict__ mup = mu + lane * DD;
  const float* __restrict__ ivp = iv + lane * DD;
  float acc = 0.f;
  #pragma unroll
  for (int d = 0; d < DD; ++d){
    float diff = xp[d] - mup[d];
    acc = fmaf(diff * diff, ivp[d], acc);
  }
  float lx = -0.5f * (acc + cs[lane]);
  float mx = wave_max(lx);
  slx_out[row * SS + lane] = lx - mx;
}

// --- kernel 2: fused pipelined scans, one barrier per step.
// blocks [0,B): fwd; [B,2B): bwd. 768 thr = 12 waves: waves 0-3 consumers,
// waves 4-11 producers (trans tile for step s+1 into a 3-deep LDS ring).
__global__ __launch_bounds__(768) void scan_kernel(
    const float* __restrict__ slx, const float* __restrict__ mask,
    const float* __restrict__ il, const float* __restrict__ a,
    const float* __restrict__ w_base, const float* __restrict__ w_act,
    float* __restrict__ alpha, float* __restrict__ log_beta){
  const int lane = threadIdx.x & 63;
  const int w    = threadIdx.x >> 6;
  const bool is_fwd = (blockIdx.x < BB);
  const int b = is_fwd ? blockIdx.x : (blockIdx.x - BB);

  __shared__ __align__(16) float tile[3][SS * TS];  // e_ij (unnormalized), [i][j]
  __shared__ float rsp[3][8][SS];                   // producer row-sum partials
  __shared__ float fpart[2][4][SS];                 // consumer matvec partials
  __shared__ __align__(16) float aLDS[TT * AA];     // a[:, b, :] staged
  __shared__ float mLDS[TT];                        // mask[:, b] staged

  for (int idx = threadIdx.x; idx < TT * AA; idx += 768){
    int t = idx >> 3, k = idx & 7;
    aLDS[idx] = a[(t * BB + b) * AA + k];
  }
  for (int idx = threadIdx.x; idx < TT; idx += 768)
    mLDS[idx] = mask[idx * BB + b];

  if (w >= 4){
    // ======================= PRODUCERS =======================
    const int pw = w - 4;
    const int jb = pw * 8;          // 8-column chunk; lane = row i
    float wb[8], wa[8][8];
    #pragma unroll
    for (int jj = 0; jj < 8; ++jj){
      wb[jj] = w_base[lane * SS + jb + jj];
      #pragma unroll
      for (int k = 0; k < 8; ++k)
        wa[k][jj] = w_act[(k * SS + lane) * SS + jb + jj];
    }
    float aa[8], aan[8];
    {
      const int t0 = is_fwd ? 0 : (TT - 2);
      const float* __restrict__ ap = a + (t0 * BB + b) * AA;
      #pragma unroll
      for (int k = 0; k < 8; ++k) aa[k] = ap[k];
      const int t1 = is_fwd ? 1 : (TT - 3);
      const float* __restrict__ ap1 = a + (t1 * BB + b) * AA;
      #pragma unroll
      for (int k = 0; k < 8; ++k) aan[k] = ap1[k];
    }
    { // prologue: first transition -> slot 0
      float ev[8]; float racc = 0.f;
      #pragma unroll
      for (int jj = 0; jj < 8; ++jj){
        float u = wb[jj];
        #pragma unroll
        for (int k = 0; k < 8; ++k) u = fmaf(aa[k], wa[k][jj], u);
        ev[jj] = __expf(u); racc += ev[jj];
      }
      *(float4*)&tile[0][lane * TS + jb]     = make_float4(ev[0],ev[1],ev[2],ev[3]);
      *(float4*)&tile[0][lane * TS + jb + 4] = make_float4(ev[4],ev[5],ev[6],ev[7]);
      rsp[0][pw][lane] = racc;
    }
    BARRIER();
    int tw = 1;
    for (int s = 0; s < TT - 1; ++s){
      if (s <= TT - 3){
        #pragma unroll
        for (int k = 0; k < 8; ++k) aa[k] = aan[k];
        if (s + 1 <= TT - 3){
          const int tn = is_fwd ? (s + 2) : (TT - 4 - s);
          #pragma unroll
          for (int k = 0; k < 8; ++k) aan[k] = aLDS[tn * AA + k];
        }
        float ev[8]; float racc = 0.f;
        #pragma unroll
        for (int jj = 0; jj < 8; ++jj){
          float u = wb[jj];
          #pragma unroll
          for (int k = 0; k < 8; ++k) u = fmaf(aa[k], wa[k][jj], u);
          ev[jj] = __expf(u); racc += ev[jj];
        }
        *(float4*)&tile[tw][lane * TS + jb]     = make_float4(ev[0],ev[1],ev[2],ev[3]);
        *(float4*)&tile[tw][lane * TS + jb + 4] = make_float4(ev[4],ev[5],ev[6],ev[7]);
        rsp[tw][pw][lane] = racc;
        tw = (tw == 2) ? 0 : tw + 1;
      }
      BARRIER();
    }
  } else if (is_fwd){
    // ==================== FORWARD CONSUMERS ====================
    const int wb16 = __builtin_amdgcn_readfirstlane(w * 16);
    float u = __expf(slx[b * SS + lane] + il[lane]);     // unnormalized alpha_0
    float c = __builtin_amdgcn_rcpf(wave_sum_dpp(u));
    if (w == 0) alpha[b * SS + lane] = u * c;
    float slxn = slx[(BB + b) * SS + lane];              // slx[t=1]
    float elxc = 0.f;
    BARRIER();
    int ts = 0;
    for (int s = 0; s < TT - 1; ++s){
      if (s > 0){
        const int fs = (s - 1) & 1;
        float S = (fpart[fs][0][lane] + fpart[fs][1][lane])
                + (fpart[fs][2][lane] + fpart[fs][3][lane]);
        u = elxc * fmaf(c, S, SEPS);                     // alpha_s (unnormalized)
        c = __builtin_amdgcn_rcpf(wave_sum_dpp(u));      // off critical path (DPP)
        if (w == 0) alpha[(s * BB + b) * SS + lane] = u * c;
      }
      float rs = ((rsp[ts][0][lane] + rsp[ts][1][lane]) + (rsp[ts][2][lane] + rsp[ts][3][lane]))
               + ((rsp[ts][4][lane] + rsp[ts][5][lane]) + (rsp[ts][6][lane] + rsp[ts][7][lane]));
      float va = u * __builtin_amdgcn_rcpf(rs);          // u_i / rowsum_i (lane = i)
      const float* __restrict__ tp = &tile[ts][0];
      float a0 = 0.f, a1 = 0.f, a2 = 0.f, a3 = 0.f;
      #pragma unroll
      for (int r = 0; r < 16; r += 4){
        a0 = fmaf(readlane_f(va, wb16 + r    ), tp[(wb16 + r    ) * TS + lane], a0);
        a1 = fmaf(readlane_f(va, wb16 + r + 1), tp[(wb16 + r + 1) * TS + lane], a1);
        a2 = fmaf(readlane_f(va, wb16 + r + 2), tp[(wb16 + r + 2) * TS + lane], a2);
        a3 = fmaf(readlane_f(va, wb16 + r + 3), tp[(wb16 + r + 3) * TS + lane], a3);
      }
      fpart[s & 1][w][lane] = (a0 + a1) + (a2 + a3);
      elxc = __expf(slxn);                               // for step s+1, off path
      if (s + 2 <= TT - 1) slxn = slx[((s + 2) * BB + b) * SS + lane];
      ts = (ts == 2) ? 0 : ts + 1;
      BARRIER();
    }
    { // epilogue: alpha_{T-1}
      const int fs = (TT - 2) & 1;
      float S = (fpart[fs][0][lane] + fpart[fs][1][lane])
              + (fpart[fs][2][lane] + fpart[fs][3][lane]);
      u = elxc * fmaf(c, S, SEPS);
      c = __builtin_amdgcn_rcpf(wave_sum_dpp(u));
      if (w == 0) alpha[((TT - 1) * BB + b) * SS + lane] = u * c;
    }
  } else {
    // ==================== BACKWARD CONSUMERS ====================
    // breg kept in relative form (per-(t,b) shift drops in the q_z softmax);
    // renormalized by W each step so all values stay in [ln EPS, ~0].
    const int wb16 = __builtin_amdgcn_readfirstlane(w * 16);
    float breg = 0.f, rWc = 1.f;
    if (w == 0) log_beta[((TT - 1) * BB + b) * SS + lane] = 0.f;
    float slxc = slx[((TT - 1) * BB + b) * SS + lane];
    float mprev = 1.f;
    BARRIER();
    int ts = 0, pts = 2;
    for (int s = 0; s < TT - 1; ++s){
      if (s > 0){
        const int fs = (s - 1) & 1;
        float eh = (fpart[fs][0][lane] + fpart[fs][1][lane])
                 + (fpart[fs][2][lane] + fpart[fs][3][lane]);
        float rsv = ((rsp[pts][0][lane] + rsp[pts][1][lane]) + (rsp[pts][2][lane] + rsp[pts][3][lane]))
                  + ((rsp[pts][4][lane] + rsp[pts][5][lane]) + (rsp[pts][6][lane] + rsp[pts][7][lane]));
        // v = log( sum_j (tr_ij + EPS) * wgt_j / W )  (shift-relative LSE)
        float v = __logf(fmaf(eh * __builtin_amdgcn_rcpf(rsv), rWc, EPSF));
        breg = (mprev == 1.0f) ? v : 0.0f;
        if (w == 0) log_beta[((TT - 1 - s) * BB + b) * SS + lane] = breg;
      }
      float wgt = __expf(slxc + breg);                   // lane = j
      float W = wave_sum_dpp(wgt);                       // overlaps matvec (VALU)
      rWc = __builtin_amdgcn_rcpf(W);                    // consumed next iter
      const float* __restrict__ tp = &tile[ts][lane * TS + wb16];
      float4 e0 = *(const float4*)(tp);
      float4 e1 = *(const float4*)(tp + 4);
      float4 e2 = *(const float4*)(tp + 8);
      float4 e3 = *(const float4*)(tp + 12);
      float a0 = 0.f, a1 = 0.f, a2 = 0.f, a3 = 0.f;
      a0 = fmaf(readlane_f(wgt, wb16 + 0),  e0.x, a0);
      a1 = fmaf(readlane_f(wgt, wb16 + 1),  e0.y, a1);
      a2 = fmaf(readlane_f(wgt, wb16 + 2),  e0.z, a2);
      a3 = fmaf(readlane_f(wgt, wb16 + 3),  e0.w, a3);
      a0 = fmaf(readlane_f(wgt, wb16 + 4),  e1.x, a0);
      a1 = fmaf(readlane_f(wgt, wb16 + 5),  e1.y, a1);
      a2 = fmaf(readlane_f(wgt, wb16 + 6),  e1.z, a2);
      a3 = fmaf(readlane_f(wgt, wb16 + 7),  e1.w, a3);
      a0 = fmaf(readlane_f(wgt, wb16 + 8),  e2.x, a0);
      a1 = fmaf(readlane_f(wgt, wb16 + 9),  e2.y, a1);
      a2 = fmaf(readlane_f(wgt, wb16 + 10), e2.z, a2);
      a3 = fmaf(readlane_f(wgt, wb16 + 11), e2.w, a3);
      a0 = fmaf(readlane_f(wgt, wb16 + 12), e3.x, a0);
      a1 = fmaf(readlane_f(wgt, wb16 + 13), e3.y, a1);
      a2 = fmaf(readlane_f(wgt, wb16 + 14), e3.z, a2);
      a3 = fmaf(readlane_f(wgt, wb16 + 15), e3.w, a3);
      fpart[s & 1][w][lane] = (a0 + a1) + (a2 + a3);
      mprev = mLDS[TT - 1 - s];
      if (s <= TT - 3) slxc = slx[((TT - 2 - s) * BB + b) * SS + lane];
      pts = ts; ts = (ts == 2) ? 0 : ts + 1;
      BARRIER();
    }
    { // epilogue: breg_0
      const int fs = (TT - 2) & 1;
      float eh = (fpart[fs][0][lane] + fpart[fs][1][lane])
               + (fpart[fs][2][lane] + fpart[fs][3][lane]);
      float rsv = ((rsp[pts][0][lane] + rsp[pts][1][lane]) + (rsp[pts][2][lane] + rsp[pts][3][lane]))
                + ((rsp[pts][4][lane] + rsp[pts][5][lane]) + (rsp[pts][6][lane] + rsp[pts][7][lane]));
      float v = __logf(fmaf(eh * __builtin_amdgcn_rcpf(rsv), rWc, EPSF));
      breg = (mprev == 1.0f) ? v : 0.0f;
      if (w == 0) log_beta[b * SS + lane] = breg;
    }
  }
}

// --- kernel 3: q_z = softmax(log(alpha+EPS) + log_beta) over states
__global__ __launch_bounds__(256) void qz_kernel(
    const float* __restrict__ alpha, const float* __restrict__ log_beta,
    float* __restrict__ out){
  const int lane = threadIdx.x & 63;
  const int w = threadIdx.x >> 6;
  const int row = blockIdx.x * 4 + w;
  float v = __logf(alpha[row * SS + lane] + EPSF) + log_beta[row * SS + lane];
  float mx = wave_max(v);
  float e = __expf(v - mx);
  float sm = wave_sum(e);
  out[row * SS + lane] = e * __builtin_amdgcn_rcpf(sm);
}

extern "C" void kernel_launch(void* const* d_in, const int* in_sizes, int n_in,
                              void* d_out, int out_size, void* d_ws, size_t ws_size,
                              hipStream_t stream){
  const float* x      = (const float*)d_in[0];
  const float* a      = (const float*)d_in[1];
  const float* mask   = (const float*)d_in[2];
  const float* mu     = (const float*)d_in[3];
  const float* logv   = (const float*)d_in[4];
  const float* il     = (const float*)d_in[5];
  const float* w_base = (const float*)d_in[6];
  const float* w_act  = (const float*)d_in[7];
  float* out = (float*)d_out;

  float* ws = (float*)d_ws;
  const size_t TBS = (size_t)TT * BB * SS;
  float* iv       = ws;               // 2048 (+ cs, padded to 4096)
  float* cs       = ws + 2048;
  float* slx      = ws + 4096;        // TBS
  float* alpha    = slx + TBS;        // TBS
  float* log_beta = alpha + TBS;      // TBS  -> 12.6 MB total

  prep_kernel<<<8, 256, 0, stream>>>(logv, iv, cs);
  logpx_kernel<<<TT * BB / 4, 256, 0, stream>>>(x, mu, iv, cs, slx);
  scan_kernel<<<2 * BB, 768, 0, stream>>>(slx, mask, il, a, w_base, w_act,
                                          alpha, log_beta);
  qz_kernel<<<TT * BB / 4, 256, 0, stream>>>(alpha, log_beta, out);
}